// Round 1
// baseline (261.192 us; speedup 1.0000x reference)
//
#include <hip/hip_runtime.h>
#include <stdint.h>

#define D_DIM   4096
#define THREADS 256
// 16 elements per thread = 4 x float4

__device__ __forceinline__ int wave_reduce_add(int v) {
    #pragma unroll
    for (int m = 32; m >= 1; m >>= 1) v += __shfl_xor(v, m, 64);
    return v;
}
__device__ __forceinline__ uint32_t wave_reduce_min(uint32_t v) {
    #pragma unroll
    for (int m = 32; m >= 1; m >>= 1) {
        uint32_t o = (uint32_t)__shfl_xor((int)v, m, 64);
        v = (o < v) ? o : v;
    }
    return v;
}
__device__ __forceinline__ uint32_t wave_reduce_max(uint32_t v) {
    #pragma unroll
    for (int m = 32; m >= 1; m >>= 1) {
        uint32_t o = (uint32_t)__shfl_xor((int)v, m, 64);
        v = (o > v) ? o : v;
    }
    return v;
}

__global__ __launch_bounds__(THREADS, 4)
void kwta_kernel(const float* __restrict__ x, const int* __restrict__ kptr,
                 float* __restrict__ out) {
    const int row  = blockIdx.x;
    const int t    = threadIdx.x;
    const int wid  = t >> 6;   // wave id 0..3
    const int lane = t & 63;
    const size_t base = (size_t)row * D_DIM;
    const float4* __restrict__ xr = reinterpret_cast<const float4*>(x + base);
    float4* __restrict__ orow     = reinterpret_cast<float4*>(out + base);
    const int k = kptr[0];

    // Load 16 elements (coalesced float4) and map to order-preserving uint.
    uint32_t u[16];
    #pragma unroll
    for (int j = 0; j < 4; ++j) {
        float4 v = xr[t + j * THREADS];
        uint32_t b[4] = { __float_as_uint(v.x), __float_as_uint(v.y),
                          __float_as_uint(v.z), __float_as_uint(v.w) };
        #pragma unroll
        for (int e = 0; e < 4; ++e) {
            uint32_t f = b[e];
            u[j * 4 + e] = ((int32_t)f < 0) ? ~f : (f | 0x80000000u);
        }
    }

    // Row min/max to tighten the bisection range.
    uint32_t mn = 0xFFFFFFFFu, mx = 0u;
    #pragma unroll
    for (int e = 0; e < 16; ++e) {
        mn = (u[e] < mn) ? u[e] : mn;
        mx = (u[e] > mx) ? u[e] : mx;
    }
    mn = wave_reduce_min(mn);
    mx = wave_reduce_max(mx);

    __shared__ uint32_t smn[4], smx[4];
    __shared__ int      scnt[4];
    if (lane == 0) { smn[wid] = mn; smx[wid] = mx; }
    __syncthreads();
    uint32_t lo = smn[0]; lo = (smn[1] < lo) ? smn[1] : lo;
             lo = (smn[2] < lo) ? smn[2] : lo; lo = (smn[3] < lo) ? smn[3] : lo;
    uint32_t hi = smx[0]; hi = (smx[1] > hi) ? smx[1] : hi;
             hi = (smx[2] > hi) ? smx[2] : hi; hi = (smx[3] > hi) ? smx[3] : hi;

    // Invariant: count(u >= lo) >= k; answer (k-th largest bit pattern) in [lo, hi].
    #pragma unroll 1
    while (lo < hi) {
        uint32_t diff = hi - lo;
        uint32_t mid  = lo + (diff >> 1) + (diff & 1u);  // upper mid, overflow-safe
        int c = 0;
        #pragma unroll
        for (int e = 0; e < 16; ++e) c += (u[e] >= mid) ? 1 : 0;
        c = wave_reduce_add(c);
        __syncthreads();                   // WAR: scnt read last iteration
        if (lane == 0) scnt[wid] = c;
        __syncthreads();
        int total = scnt[0] + scnt[1] + scnt[2] + scnt[3];
        if (total >= k) lo = mid; else hi = mid - 1u;
    }

    const uint32_t thr = lo;
    #pragma unroll
    for (int j = 0; j < 4; ++j) {
        float4 o;
        float* po = &o.x;
        #pragma unroll
        for (int e = 0; e < 4; ++e) {
            uint32_t uu = u[j * 4 + e];
            uint32_t f  = (uu & 0x80000000u) ? (uu ^ 0x80000000u) : ~uu;
            po[e] = (uu >= thr) ? __uint_as_float(f) : 0.0f;
        }
        orow[t + j * THREADS] = o;
    }
}

extern "C" void kernel_launch(void* const* d_in, const int* in_sizes, int n_in,
                              void* d_out, int out_size, void* d_ws, size_t ws_size,
                              hipStream_t stream) {
    const float* x    = (const float*)d_in[0];
    const int*   kptr = (const int*)d_in[1];
    float*       out  = (float*)d_out;
    const int rows = out_size / D_DIM;   // 8192
    kwta_kernel<<<rows, THREADS, 0, stream>>>(x, kptr, out);
}